// Round 4
// baseline (3673.798 us; speedup 1.0000x reference)
//
#include <hip/hip_runtime.h>
#include <hip/hip_bf16.h>
#include <math.h>

// Problem constants
#define Bb   128
#define Ss   64
#define Tt   50
#define Ff   100
#define DAa  350
#define Rr   30
#define HFCc 100
#define Hh   100
#define PITCH 352   // row pitch (floats) for xW chunk and WT (350 padded to 352)
#define UP    356   // padded d-length (356 = 4*89 quads), zero-padded 350..355

// ws layout (float indices), all 16B-aligned:
#define WS_WT    0        // 100 x 352            = 35200
#define WS_UPAD  35200    // 30 x 356             = 10680
#define WS_WCT   45880    // 100 x 356            = 35600
#define WS_BPAD  81480    // 356 (+ pad to 81840)
#define WS_HST   81840    // 128 x 100            = 12800
#define WS_XW    94640    // SC * 128 * 50 * 352

// ---------------------------------------------------------------------------
// Prep: WT[k][col]=W[col][k] (100x352); u_pad[r][d] (30x356, zero pad);
// WcT[k][d]=Wc[d][k] (100x356, zero pad); b_pad[d] (356, zero pad).
// ---------------------------------------------------------------------------
__global__ __launch_bounds__(256) void k_prep(const float* __restrict__ W,
                                              const float* __restrict__ u,
                                              const float* __restrict__ Wc,
                                              const float* __restrict__ bvec,
                                              float* __restrict__ ws) {
  int i = blockIdx.x * 256 + threadIdx.x;
  if (i < 100 * PITCH) {
    int k = i / PITCH, col = i % PITCH;
    ws[WS_WT + i] = (col < DAa) ? W[col * Ff + k] : 0.0f;
  }
  if (i < Rr * UP) {
    int r = i / UP, d = i % UP;
    ws[WS_UPAD + i] = (d < DAa) ? u[r * DAa + d] : 0.0f;
  }
  if (i < Hh * UP) {
    int k = i / UP, d = i % UP;
    ws[WS_WCT + i] = (d < DAa) ? Wc[d * Hh + k] : 0.0f;
  }
  if (i < UP) {
    ws[WS_BPAD + i] = (i < DAa) ? bvec[i] : 0.0f;
  }
}

// ---------------------------------------------------------------------------
// xW chunk GEMM (unchanged): BM=64, BN=128, K=100. grid=(100*SC,3), block=256.
// ---------------------------------------------------------------------------
__global__ __launch_bounds__(256) void k_gemm(const float* __restrict__ x,
                                              const float* __restrict__ WT,
                                              float* __restrict__ xw,
                                              int c, int SC) {
  __shared__ __align__(16) float As[64][108];   // [m][k]
  __shared__ __align__(16) float Bs[100][128];  // [k][col]
  const int tid = threadIdx.x;
  const int mt = blockIdx.x;
  const int nt = blockIdx.y;
  const int rowsPerB = SC * Tt;

  for (int i = tid; i < 1600; i += 256) {
    int m = i / 25, k4 = (i % 25) * 4;
    int rch = mt * 64 + m;
    int b = rch / rowsPerB, rem = rch % rowsPerB;
    int sl = rem / Tt, t = rem % Tt;
    const float4 v = *(const float4*)&x[((size_t)((b * Ss + c * SC + sl) * Tt) + t) * Ff + k4];
    *(float4*)&As[m][k4] = v;
  }
  for (int i = tid; i < 3200; i += 256) {
    int k = i / 32, j4 = (i % 32) * 4;
    int col4 = nt * 128 + j4;
    float4 v = make_float4(0.f, 0.f, 0.f, 0.f);
    if (col4 < PITCH) v = *(const float4*)&WT[k * PITCH + col4];
    *(float4*)&Bs[k][j4] = v;
  }
  __syncthreads();

  const int tx = tid % 16, ty = tid / 16;
  float acc[4][8];
#pragma unroll
  for (int i = 0; i < 4; ++i)
#pragma unroll
    for (int j = 0; j < 8; ++j) acc[i][j] = 0.f;

#pragma unroll 4
  for (int k = 0; k < 100; ++k) {
    float a[4];
#pragma unroll
    for (int i = 0; i < 4; ++i) a[i] = As[ty * 4 + i][k];
    float4 b0 = *(float4*)&Bs[k][tx * 8];
    float4 b1 = *(float4*)&Bs[k][tx * 8 + 4];
#pragma unroll
    for (int i = 0; i < 4; ++i) {
      acc[i][0] += a[i] * b0.x; acc[i][1] += a[i] * b0.y;
      acc[i][2] += a[i] * b0.z; acc[i][3] += a[i] * b0.w;
      acc[i][4] += a[i] * b1.x; acc[i][5] += a[i] * b1.y;
      acc[i][6] += a[i] * b1.z; acc[i][7] += a[i] * b1.w;
    }
  }

  const int col4 = nt * 128 + tx * 8;
#pragma unroll
  for (int i = 0; i < 4; ++i) {
    int rch = mt * 64 + ty * 4 + i;
    float* dst = &xw[(size_t)rch * PITCH + col4];
    if (col4 <= 348)
      *(float4*)dst = make_float4(acc[i][0], acc[i][1], acc[i][2], acc[i][3]);
    if (col4 + 4 <= 348)
      *(float4*)(dst + 4) = make_float4(acc[i][4], acc[i][5], acc[i][6], acc[i][7]);
  }
}

// ---------------------------------------------------------------------------
// Persistent per-b scan. grid = 128, block = 1024 (16 waves, 4/SIMD).
// All heavy phases remapped to exploit 16 waves; LDS scratch overlaid.
// ---------------------------------------------------------------------------
__global__ __launch_bounds__(1024) void k_scan(
    const float* __restrict__ x, const float* __restrict__ xw,
    const float* __restrict__ WcT, const float* __restrict__ b_pad,
    const float* __restrict__ u_pad, const float* __restrict__ Wfc,
    const float* __restrict__ bfc,
    const float* __restrict__ Wz, const float* __restrict__ Wr,
    const float* __restrict__ Wh, const float* __restrict__ Uz,
    const float* __restrict__ Ur, const float* __restrict__ Uh,
    const float* __restrict__ bz, const float* __restrict__ br,
    const float* __restrict__ bh,
    float* __restrict__ out, float* __restrict__ hstate, int c, int SC) {
  __shared__ __align__(16) float uit_s[Tt][UP];   // 71.2 KB
  __shared__ __align__(16) float scratch[12800];  // 51.2 KB overlay
  __shared__ __align__(16) float ait_s[Rr * Tt];  // 6 KB; [t*30+r] == reshaped [r*50+t]
  __shared__ __align__(16) float M_s[Rr][104];    // 12.5 KB
  __shared__ __align__(16) float ctx_s[UP];
  __shared__ __align__(16) float h_sm[Hh];
  __shared__ __align__(16) float fc_sm[HFCc];
  __shared__ float z_sm[Hh], r_sm[Hh], rh_sm[Hh], hc1_sm[Hh];

  const int tid = threadIdx.x;
  const int b = blockIdx.x;
  const int lane = tid & 63;
  const int w = tid >> 6;                      // 0..15
  const int wu = __builtin_amdgcn_readfirstlane(w);
  const int seg = wu & 7;                      // d-segment for ait
  const int half = wu >> 3;                    // r-half for ait (0: r0-14, 1: r15-29)
  const int q0 = seg * 11;
  const int q1 = (seg == 7) ? 89 : q0 + 11;
  const int tl = (lane < Tt) ? lane : (Tt - 1);

  if (tid < Tt * 4) uit_s[tid >> 2][352 + (tid & 3)] = 0.f;
  if (tid < Hh) h_sm[tid] = (c == 0) ? 0.f : hstate[b * Hh + tid];
  __syncthreads();

  for (int sl = 0; sl < SC; ++sl) {
    const int sg = c * SC + sl;

    // ---- ctx partials: 712 threads = (ks in [0,8)) x (dq in [0,89))
    if (tid < 712) {
      const int ks = tid / 89, dq = tid % 89;
      const int k0 = (ks < 4) ? 13 * ks : 52 + 12 * (ks - 4);
      const int kl = (ks < 4) ? 13 : 12;
      float4 a = make_float4(0.f, 0.f, 0.f, 0.f);
      const float* wp = &WcT[k0 * UP + dq * 4];
      for (int k = 0; k < kl; ++k) {
        const float hk = h_sm[k0 + k];
        const float4 wv = *(const float4*)&wp[k * UP];
        a.x = fmaf(wv.x, hk, a.x); a.y = fmaf(wv.y, hk, a.y);
        a.z = fmaf(wv.z, hk, a.z); a.w = fmaf(wv.w, hk, a.w);
      }
      *(float4*)&scratch[ks * UP + dq * 4] = a;
    }
    __syncthreads();
    if (tid < 356) {
      float v = b_pad[tid];
#pragma unroll
      for (int ks = 0; ks < 8; ++ks) v += scratch[ks * UP + tid];
      ctx_s[tid] = v;
    }
    __syncthreads();

    // ---- uit[t][q*4..] = tanh(xw + ctx): all 1024 threads, ~4.3 f4/thread
    {
      const size_t rbase = (size_t)(b * SC + sl) * Tt;
      for (int e = tid; e < Tt * 88; e += 1024) {
        int t = e / 88, q = e % 88;
        float4 v = *(const float4*)&xw[(rbase + t) * PITCH + q * 4];
        const float4 cv = *(const float4*)&ctx_s[q * 4];
        v.x = tanhf(v.x + cv.x); v.y = tanhf(v.y + cv.y);
        v.z = tanhf(v.z + cv.z); v.w = tanhf(v.w + cv.w);
        *(float4*)&uit_s[t][q * 4] = v;
      }
    }
    __syncthreads();

    // ---- ait partials: 16 waves = 8 d-segs x 2 r-halves; lane = t.
    // u rows via wave-uniform addresses -> scalar loads.
    {
      float pacc[15];
#pragma unroll
      for (int ri = 0; ri < 15; ++ri) pacc[ri] = 0.f;
      for (int q = q0; q < q1; ++q) {
        const float4 tv = *(const float4*)&uit_s[tl][q * 4];
#pragma unroll
        for (int ri = 0; ri < 15; ++ri) {
          const float4 uv = *(const float4*)&u_pad[(half * 15 + ri) * UP + q * 4];
          pacc[ri] = fmaf(tv.x, uv.x,
                      fmaf(tv.y, uv.y,
                       fmaf(tv.z, uv.z,
                        fmaf(tv.w, uv.w, pacc[ri]))));
        }
      }
      if (lane < Tt) {
        // transposed scalar stores: consecutive lanes -> consecutive addrs
#pragma unroll
        for (int ri = 0; ri < 15; ++ri)
          scratch[w * 800 + ri * Tt + lane] = pacc[ri];
      }
    }
    __syncthreads();

    // ---- reduce 8 d-seg partials -> ait_s[t*30+r]
    for (int o = tid; o < Tt * Rr; o += 1024) {
      const int t = o / Rr, r = o % Rr;
      const int hf = (r >= 15) ? 1 : 0;
      const int ri = r - hf * 15;
      float s = 0.f;
#pragma unroll
      for (int sg2 = 0; sg2 < 8; ++sg2)
        s += scratch[(hf * 8 + sg2) * 800 + ri * Tt + t];
      ait_s[o] = s;
    }
    __syncthreads();

    // ---- softmax over reinterpreted rows: row rr = ait_s[rr*50 .. rr*50+49]
    if (tid < 480) {
      int rr = tid >> 4, l = tid & 15;
      float m = -1e30f;
      for (int t = l; t < Tt; t += 16) m = fmaxf(m, ait_s[rr * Tt + t]);
#pragma unroll
      for (int o = 8; o >= 1; o >>= 1) m = fmaxf(m, __shfl_xor(m, o, 16));
      float ssum = 0.f;
      for (int t = l; t < Tt; t += 16) ssum += expf(ait_s[rr * Tt + t] - m);
#pragma unroll
      for (int o = 8; o >= 1; o >>= 1) ssum += __shfl_xor(ssum, o, 16);
      float inv = 1.0f / ssum;
      for (int t = l; t < Tt; t += 16)
        ait_s[rr * Tt + t] = expf(ait_s[rr * Tt + t] - m) * inv;
    }
    __syncthreads();

    // ---- M[r][f] = sum_t A[r][t] * x[b,sg,t,f]: 1000 threads, 3 r's each
    if (tid < 1000) {
      int f = tid % 100, q = tid / 100, r0 = q * 3;
      float acc[3] = {0.f, 0.f, 0.f};
      const float* xp = &x[((size_t)(b * Ss + sg) * Tt) * Ff + f];
      for (int t = 0; t < Tt; ++t) {
        float xv = xp[(size_t)t * Ff];
#pragma unroll
        for (int i2 = 0; i2 < 3; ++i2) acc[i2] += ait_s[(r0 + i2) * Tt + t] * xv;
      }
#pragma unroll
      for (int i2 = 0; i2 < 3; ++i2) M_s[r0 + i2][f] = acc[i2];
    }
    __syncthreads();

    // ---- fc partials: 750 threads = (r in [0,30)) x (jq in [0,25))
    if (tid < 750) {
      const int r = tid / 25, jq = tid % 25;
      float4 a = make_float4(0.f, 0.f, 0.f, 0.f);
      const float* wp = &Wfc[(size_t)(r * 100) * 100 + jq * 4];
#pragma unroll 4
      for (int f2 = 0; f2 < 100; ++f2) {
        const float mv = M_s[r][f2];
        const float4 wv = *(const float4*)&wp[(size_t)f2 * 100];
        a.x = fmaf(mv, wv.x, a.x); a.y = fmaf(mv, wv.y, a.y);
        a.z = fmaf(mv, wv.z, a.z); a.w = fmaf(mv, wv.w, a.w);
      }
      *(float4*)&scratch[r * 100 + jq * 4] = a;
    }
    __syncthreads();
    if (tid < 100) {
      float v = bfc[tid];
#pragma unroll
      for (int r = 0; r < 30; ++r) v += scratch[r * 100 + tid];
      fc_sm[tid] = fmaxf(v, 0.f);
    }
    __syncthreads();

    // ---- GRU partials: 500 threads = pair(5) x ks(4) x jq(25)
    // pair: 0=fc*Wz 1=h*Uz 2=fc*Wr 3=h*Ur 4=fc*Wh
    if (tid < 500) {
      const int pair = tid / 100, rem = tid % 100, ks = rem / 25, jq = rem % 25;
      const float* Wm = (pair == 0) ? Wz : (pair == 1) ? Uz : (pair == 2) ? Wr
                        : (pair == 3) ? Ur : Wh;
      const float* vin = (pair == 1 || pair == 3) ? h_sm : fc_sm;
      float4 a = make_float4(0.f, 0.f, 0.f, 0.f);
      const float* wp = &Wm[ks * 25 * 100 + jq * 4];
#pragma unroll 5
      for (int k = 0; k < 25; ++k) {
        const float fv = vin[ks * 25 + k];
        const float4 wv = *(const float4*)&wp[k * 100];
        a.x = fmaf(fv, wv.x, a.x); a.y = fmaf(fv, wv.y, a.y);
        a.z = fmaf(fv, wv.z, a.z); a.w = fmaf(fv, wv.w, a.w);
      }
      *(float4*)&scratch[(pair * 4 + ks) * 100 + jq * 4] = a;
    }
    __syncthreads();
    if (tid < 300) {
      const int unit = tid / 100, j = tid % 100;
      if (unit == 0) {
        float a = bz[j];
#pragma unroll
        for (int i = 0; i < 8; ++i) a += scratch[i * 100 + j];
        z_sm[j] = 1.0f / (1.0f + expf(-a));
      } else if (unit == 1) {
        float a = br[j];
#pragma unroll
        for (int i = 8; i < 16; ++i) a += scratch[i * 100 + j];
        r_sm[j] = 1.0f / (1.0f + expf(-a));
      } else {
        float a = bh[j];
#pragma unroll
        for (int i = 16; i < 20; ++i) a += scratch[i * 100 + j];
        hc1_sm[j] = a;
      }
    }
    __syncthreads();
    if (tid < 100) rh_sm[tid] = r_sm[tid] * h_sm[tid];
    __syncthreads();

    // ---- hp partials: 100 threads = ks(4) x jq(25)
    if (tid < 100) {
      const int ks = tid / 25, jq = tid % 25;
      float4 a = make_float4(0.f, 0.f, 0.f, 0.f);
      const float* up = &Uh[ks * 25 * 100 + jq * 4];
#pragma unroll 5
      for (int k = 0; k < 25; ++k) {
        const float rv = rh_sm[ks * 25 + k];
        const float4 uv = *(const float4*)&up[k * 100];
        a.x = fmaf(rv, uv.x, a.x); a.y = fmaf(rv, uv.y, a.y);
        a.z = fmaf(rv, uv.z, a.z); a.w = fmaf(rv, uv.w, a.w);
      }
      *(float4*)&scratch[ks * 100 + jq * 4] = a;
    }
    __syncthreads();
    if (tid < 100) {
      const int j = tid;
      float acc = hc1_sm[j] + scratch[j] + scratch[100 + j] + scratch[200 + j] + scratch[300 + j];
      float hp = tanhf(acc);
      float z = z_sm[j];
      float hn = (1.0f - z) * h_sm[j] + z * hp;
      out[((size_t)b * Ss + sg) * Hh + j] = hn;
      h_sm[j] = hn;  // only thread j reads h_sm[j] in this phase
    }
    __syncthreads();
  }

  if (tid < Hh) hstate[b * Hh + tid] = h_sm[tid];
}

// ---------------------------------------------------------------------------
extern "C" void kernel_launch(void* const* d_in, const int* in_sizes, int n_in,
                              void* d_out, int out_size, void* d_ws, size_t ws_size,
                              hipStream_t stream) {
  const float* x   = (const float*)d_in[0];
  const float* W   = (const float*)d_in[1];
  const float* Wc  = (const float*)d_in[2];
  const float* bv  = (const float*)d_in[3];
  const float* u   = (const float*)d_in[4];
  const float* Wfc = (const float*)d_in[5];
  const float* bfc = (const float*)d_in[6];
  const float* Wz  = (const float*)d_in[7];
  const float* Wr  = (const float*)d_in[8];
  const float* Wh  = (const float*)d_in[9];
  const float* Uz  = (const float*)d_in[10];
  const float* Ur  = (const float*)d_in[11];
  const float* Uh  = (const float*)d_in[12];
  const float* bz  = (const float*)d_in[13];
  const float* br  = (const float*)d_in[14];
  const float* bh  = (const float*)d_in[15];
  float* out = (float*)d_out;
  float* ws  = (float*)d_ws;

  int SC = 8;  // sentences per chunk; xw chunk = SC*2252800 floats (~72 MB @ 8)
  while (SC > 1 && ((size_t)WS_XW + (size_t)SC * 2252800) * 4 > ws_size) SC >>= 1;
  const int NC = Ss / SC;

  float* WT   = ws + WS_WT;
  float* upad = ws + WS_UPAD;
  float* WcT  = ws + WS_WCT;
  float* bpad = ws + WS_BPAD;
  float* hst  = ws + WS_HST;
  float* xw   = ws + WS_XW;

  k_prep<<<140, 256, 0, stream>>>(W, u, Wc, bv, ws);
  for (int c = 0; c < NC; ++c) {
    k_gemm<<<dim3(100 * SC, 3), 256, 0, stream>>>(x, WT, xw, c, SC);
    k_scan<<<128, 1024, 0, stream>>>(x, xw, WcT, bpad, upad, Wfc, bfc,
                                     Wz, Wr, Wh, Uz, Ur, Uh, bz, br, bh,
                                     out, hst, c, SC);
  }
}

// Round 5
// 3592.840 us; speedup vs baseline: 1.0225x; 1.0225x over previous
//
#include <hip/hip_runtime.h>
#include <hip/hip_bf16.h>
#include <math.h>

// Problem constants
#define Bb   128
#define Ss   64
#define Tt   50
#define Ff   100
#define DAa  350
#define Rr   30
#define HFCc 100
#define Hh   100
#define PITCH 352   // row pitch (floats) for xw chunk and WT
#define UP    356   // padded d-length (4*89 quads), zero-padded 350..355

// ws layout (float indices), 16B-aligned:
#define WS_WT    0        // 100 x 352 = 35200
#define WS_UPAD  35200    // 30 x 356  = 10680
#define WS_WCT   45880    // 100 x 356 = 35600
#define WS_BPAD  81480    // 356 (pad to 81840)
#define WS_HST   81840    // 128 x 100 = 12800
#define WS_XW    94640    // two chunk buffers, each SC*2252800 floats

#define SCAN_BLOCKS 128
#define CHUNK_F 2252800   // floats per SC=1 chunk unit (128*50*352)

// ---------------------------------------------------------------------------
__global__ __launch_bounds__(256) void k_prep(const float* __restrict__ W,
                                              const float* __restrict__ u,
                                              const float* __restrict__ Wc,
                                              const float* __restrict__ bvec,
                                              float* __restrict__ ws) {
  int i = blockIdx.x * 256 + threadIdx.x;
  if (i < 100 * PITCH) {
    int k = i / PITCH, col = i % PITCH;
    ws[WS_WT + i] = (col < DAa) ? W[col * Ff + k] : 0.0f;
  }
  if (i < Rr * UP) {
    int r = i / UP, d = i % UP;
    ws[WS_UPAD + i] = (d < DAa) ? u[r * DAa + d] : 0.0f;
  }
  if (i < Hh * UP) {
    int k = i / UP, d = i % UP;
    ws[WS_WCT + i] = (d < DAa) ? Wc[d * Hh + k] : 0.0f;
  }
  if (i < UP) ws[WS_BPAD + i] = (i < DAa) ? bvec[i] : 0.0f;
}

// ---------------------------------------------------------------------------
// Fused kernel. Blocks [0,128) (when doScan): persistent per-b scan of chunk c
// reading xwRead. Remaining blocks: GEMM tiles of chunk gemmChunk -> xwWrite.
// Both roles: 1024 threads. Shared memory is one carved arena (144.3 KB).
// ---------------------------------------------------------------------------
__global__ __launch_bounds__(1024) void k_fused(
    const float* __restrict__ x, const float* __restrict__ WT,
    const float* __restrict__ xwRead, float* __restrict__ xwWrite,
    const float* __restrict__ WcT, const float* __restrict__ b_pad,
    const float* __restrict__ u_pad, const float* __restrict__ Wfc,
    const float* __restrict__ bfc,
    const float* __restrict__ Wz, const float* __restrict__ Wr,
    const float* __restrict__ Wh, const float* __restrict__ Uz,
    const float* __restrict__ Ur, const float* __restrict__ Uh,
    const float* __restrict__ bz, const float* __restrict__ br,
    const float* __restrict__ bh,
    float* __restrict__ out, float* __restrict__ hstate,
    int c, int SC, int doScan, int gemmChunk, int nGemm) {
  __shared__ __align__(16) float smem[36076];  // 144.3 KB arena

  const int tid = threadIdx.x;
  const int bid = blockIdx.x;

  if (doScan && bid < SCAN_BLOCKS) {
    // ---------------- scan role ----------------
    float* uit     = smem;            // 50 x 356 = 17800
    float* scratch = smem + 17800;    // 12800
    float* ait     = smem + 30600;    // 1500 (stored in reshaped layout [r*50+t])
    float* M_s     = smem + 32100;    // 30 x 104 = 3120
    float* ctx     = smem + 35220;    // 356
    float* h_sm    = smem + 35576;    // 100
    float* fc_sm   = smem + 35676;    // 100
    float* z_sm    = smem + 35776;    // 100
    float* rg_sm   = smem + 35876;    // 100
    float* hc1_sm  = smem + 35976;    // 100

    const int b = bid;
    const int lane = tid & 63;
    const int w = tid >> 6;                      // 0..15
    const int wu = __builtin_amdgcn_readfirstlane(w);
    const int seg = wu & 7;                      // d-segment
    const int half = wu >> 3;                    // r-half
    const int q0 = seg * 11;
    const int q1 = (seg == 7) ? 89 : q0 + 11;
    const int tl = (lane < Tt) ? lane : (Tt - 1);

    if (tid < Tt * 4) uit[(tid >> 2) * UP + 352 + (tid & 3)] = 0.f;
    if (tid < Hh) h_sm[tid] = (c == 0) ? 0.f : hstate[b * Hh + tid];
    __syncthreads();

    for (int sl = 0; sl < SC; ++sl) {
      const int sg = c * SC + sl;

      // ---- P1: ctx partials: 712 thr = ks(8) x dq(89)
      if (tid < 712) {
        const int ks = tid / 89, dq = tid % 89;
        const int k0 = (ks < 4) ? 13 * ks : 52 + 12 * (ks - 4);
        const int kl = (ks < 4) ? 13 : 12;
        float4 a = make_float4(0.f, 0.f, 0.f, 0.f);
        const float* wp = &WcT[k0 * UP + dq * 4];
        for (int k = 0; k < kl; ++k) {
          const float hk = h_sm[k0 + k];
          const float4 wv = *(const float4*)&wp[k * UP];
          a.x = fmaf(wv.x, hk, a.x); a.y = fmaf(wv.y, hk, a.y);
          a.z = fmaf(wv.z, hk, a.z); a.w = fmaf(wv.w, hk, a.w);
        }
        *(float4*)&scratch[ks * UP + dq * 4] = a;
      }
      __syncthreads();
      // ---- P2: ctx combine
      if (tid < 356) {
        float v = b_pad[tid];
#pragma unroll
        for (int ks = 0; ks < 8; ++ks) v += scratch[ks * UP + tid];
        ctx[tid] = v;
      }
      __syncthreads();

      // ---- P3: uit = tanh(xw + ctx)
      {
        const size_t rbase = (size_t)(b * SC + sl) * Tt;
        for (int e = tid; e < Tt * 88; e += 1024) {
          int t = e / 88, q = e % 88;
          float4 v = *(const float4*)&xwRead[(rbase + t) * PITCH + q * 4];
          const float4 cv = *(const float4*)&ctx[q * 4];
          v.x = tanhf(v.x + cv.x); v.y = tanhf(v.y + cv.y);
          v.z = tanhf(v.z + cv.z); v.w = tanhf(v.w + cv.w);
          *(float4*)&uit[t * UP + q * 4] = v;
        }
      }
      __syncthreads();

      // ---- P4: ait partials: 16 waves = 8 d-segs x 2 r-halves; lane = t
      {
        float pacc[15];
#pragma unroll
        for (int ri = 0; ri < 15; ++ri) pacc[ri] = 0.f;
        for (int q = q0; q < q1; ++q) {
          const float4 tv = *(const float4*)&uit[tl * UP + q * 4];
#pragma unroll
          for (int ri = 0; ri < 15; ++ri) {
            const float4 uv = *(const float4*)&u_pad[(half * 15 + ri) * UP + q * 4];
            pacc[ri] = fmaf(tv.x, uv.x,
                        fmaf(tv.y, uv.y,
                         fmaf(tv.z, uv.z,
                          fmaf(tv.w, uv.w, pacc[ri]))));
          }
        }
        if (lane < Tt) {
#pragma unroll
          for (int ri = 0; ri < 15; ++ri)
            scratch[w * 800 + ri * Tt + lane] = pacc[ri];
        }
      }
      __syncthreads();

      // ---- P5: merged reduce + softmax over reshaped rows (480 thr)
      if (tid < 480) {
        const int rr = tid >> 4, l = tid & 15;
        float e[4];
        float m = -1e30f;
        int cnt = 0;
        for (int i = l; i < Tt; i += 16) {
          const int idx = rr * Tt + i;        // flat reshaped index
          const int t = idx / Rr, r = idx - t * Rr;
          const int hf = (r >= 15) ? 1 : 0, ri = r - hf * 15;
          float s = 0.f;
#pragma unroll
          for (int sg2 = 0; sg2 < 8; ++sg2)
            s += scratch[(hf * 8 + sg2) * 800 + ri * Tt + t];
          e[cnt++] = s;
          m = fmaxf(m, s);
        }
#pragma unroll
        for (int o = 8; o >= 1; o >>= 1) m = fmaxf(m, __shfl_xor(m, o, 16));
        float ssum = 0.f;
#pragma unroll 4
        for (int k = 0; k < cnt; ++k) { e[k] = expf(e[k] - m); ssum += e[k]; }
#pragma unroll
        for (int o = 8; o >= 1; o >>= 1) ssum += __shfl_xor(ssum, o, 16);
        const float inv = 1.0f / ssum;
        cnt = 0;
        for (int i = l; i < Tt; i += 16) ait[rr * Tt + i] = e[cnt++] * inv;
      }
      __syncthreads();

      // ---- P6: M[r][f] = sum_t A[r][t] * x[b,sg,t,f] (1000 thr, 3 r each)
      if (tid < 1000) {
        int f = tid % 100, q = tid / 100, r0 = q * 3;
        float acc[3] = {0.f, 0.f, 0.f};
        const float* xp = &x[((size_t)(b * Ss + sg) * Tt) * Ff + f];
        for (int t = 0; t < Tt; ++t) {
          float xv = xp[(size_t)t * Ff];
#pragma unroll
          for (int i2 = 0; i2 < 3; ++i2) acc[i2] += ait[(r0 + i2) * Tt + t] * xv;
        }
#pragma unroll
        for (int i2 = 0; i2 < 3; ++i2) M_s[(r0 + i2) * 104 + f] = acc[i2];
      }
      __syncthreads();

      // ---- P7: fc partials (750) + GRU h-side partials Uz/Ur (200)
      if (tid < 750) {
        const int r = tid / 25, jq = tid % 25;
        float4 a = make_float4(0.f, 0.f, 0.f, 0.f);
        const float* wp = &Wfc[(size_t)(r * 100) * 100 + jq * 4];
#pragma unroll 4
        for (int f2 = 0; f2 < 100; ++f2) {
          const float mv = M_s[r * 104 + f2];
          const float4 wv = *(const float4*)&wp[(size_t)f2 * 100];
          a.x = fmaf(mv, wv.x, a.x); a.y = fmaf(mv, wv.y, a.y);
          a.z = fmaf(mv, wv.z, a.z); a.w = fmaf(mv, wv.w, a.w);
        }
        *(float4*)&scratch[r * 100 + jq * 4] = a;
      } else if (tid < 950) {
        const int tt = tid - 750, pr = tt / 100, rem = tt % 100;
        const int ks = rem / 25, jq = rem % 25;
        const float* Um = pr ? Ur : Uz;
        float4 a = make_float4(0.f, 0.f, 0.f, 0.f);
        const float* up = &Um[ks * 25 * 100 + jq * 4];
#pragma unroll 5
        for (int k = 0; k < 25; ++k) {
          const float hv = h_sm[ks * 25 + k];
          const float4 uv = *(const float4*)&up[k * 100];
          a.x = fmaf(hv, uv.x, a.x); a.y = fmaf(hv, uv.y, a.y);
          a.z = fmaf(hv, uv.z, a.z); a.w = fmaf(hv, uv.w, a.w);
        }
        *(float4*)&scratch[3000 + (pr * 4 + ks) * 100 + jq * 4] = a;
      }
      __syncthreads();
      // ---- P8: fc combine
      if (tid < 100) {
        float v = bfc[tid];
#pragma unroll
        for (int r = 0; r < 30; ++r) v += scratch[r * 100 + tid];
        fc_sm[tid] = fmaxf(v, 0.f);
      }
      __syncthreads();

      // ---- P9: GRU fc-side partials Wz/Wr/Wh (300 thr)
      if (tid < 300) {
        const int p = tid / 100, rem = tid % 100, ks = rem / 25, jq = rem % 25;
        const float* Wm = (p == 0) ? Wz : (p == 1) ? Wr : Wh;
        float4 a = make_float4(0.f, 0.f, 0.f, 0.f);
        const float* wp = &Wm[ks * 25 * 100 + jq * 4];
#pragma unroll 5
        for (int k = 0; k < 25; ++k) {
          const float fv = fc_sm[ks * 25 + k];
          const float4 wv = *(const float4*)&wp[k * 100];
          a.x = fmaf(fv, wv.x, a.x); a.y = fmaf(fv, wv.y, a.y);
          a.z = fmaf(fv, wv.z, a.z); a.w = fmaf(fv, wv.w, a.w);
        }
        *(float4*)&scratch[3800 + (p * 4 + ks) * 100 + jq * 4] = a;
      }
      __syncthreads();
      // ---- P10: GRU combine
      if (tid < 300) {
        const int unit = tid / 100, j = tid % 100;
        if (unit == 0) {
          float a = bz[j];
#pragma unroll
          for (int i = 0; i < 4; ++i)
            a += scratch[3800 + i * 100 + j] + scratch[3000 + i * 100 + j];
          z_sm[j] = 1.0f / (1.0f + expf(-a));
        } else if (unit == 1) {
          float a = br[j];
#pragma unroll
          for (int i = 0; i < 4; ++i)
            a += scratch[4200 + i * 100 + j] + scratch[3400 + i * 100 + j];
          rg_sm[j] = 1.0f / (1.0f + expf(-a));
        } else {
          float a = bh[j];
#pragma unroll
          for (int i = 0; i < 4; ++i) a += scratch[4600 + i * 100 + j];
          hc1_sm[j] = a;
        }
      }
      __syncthreads();

      // ---- P11: hp partials: 500 thr = ks(20, 5 k's) x jq(25)
      if (tid < 500) {
        const int ks = tid / 25, jq = tid % 25, k0 = ks * 5;
        float4 a = make_float4(0.f, 0.f, 0.f, 0.f);
        const float* up = &Uh[k0 * 100 + jq * 4];
#pragma unroll
        for (int k = 0; k < 5; ++k) {
          const float rv = rg_sm[k0 + k] * h_sm[k0 + k];
          const float4 uv = *(const float4*)&up[k * 100];
          a.x = fmaf(rv, uv.x, a.x); a.y = fmaf(rv, uv.y, a.y);
          a.z = fmaf(rv, uv.z, a.z); a.w = fmaf(rv, uv.w, a.w);
        }
        *(float4*)&scratch[ks * 100 + jq * 4] = a;
      }
      __syncthreads();
      // ---- P12: final h update
      if (tid < 100) {
        const int j = tid;
        float a = hc1_sm[j];
#pragma unroll
        for (int ks = 0; ks < 20; ++ks) a += scratch[ks * 100 + j];
        const float hp = tanhf(a);
        const float z = z_sm[j];
        const float hn = (1.0f - z) * h_sm[j] + z * hp;
        out[((size_t)b * Ss + sg) * Hh + j] = hn;
        h_sm[j] = hn;
      }
      __syncthreads();
    }

    if (tid < Hh) hstate[b * Hh + tid] = h_sm[tid];

  } else {
    // ---------------- gemm role: BM=128, BN=128, K=100 ----------------
    const int g = doScan ? (bid - SCAN_BLOCKS) : bid;
    if (g >= nGemm) return;
    float* As = smem;            // 128 x 104 = 13312
    float* Bs = smem + 13312;    // 100 x 128 = 12800

    const int mt = g / 3, nt = g % 3;
    const int rowsPerB = SC * Tt;

    for (int i = tid; i < 3200; i += 1024) {   // A: 128 rows x 25 f4
      const int m = i / 25, k4 = (i % 25) * 4;
      const int rch = mt * 128 + m;
      const int b = rch / rowsPerB, rem = rch % rowsPerB;
      const int sl = rem / Tt, t = rem % Tt;
      *(float4*)&As[m * 104 + k4] =
          *(const float4*)&x[((size_t)((b * Ss + gemmChunk * SC + sl) * Tt) + t) * Ff + k4];
    }
    for (int i = tid; i < 3200; i += 1024) {   // B: 100 k x 32 f4
      const int k = i / 32, j4 = (i % 32) * 4;
      const int col = nt * 128 + j4;
      float4 v = make_float4(0.f, 0.f, 0.f, 0.f);
      if (col < PITCH) v = *(const float4*)&WT[k * PITCH + col];
      *(float4*)&Bs[k * 128 + j4] = v;
    }
    __syncthreads();

    const int tx = tid & 31, ty = tid >> 5;    // 32x32 threads, 4x4 each
    float acc[4][4];
#pragma unroll
    for (int i = 0; i < 4; ++i)
#pragma unroll
      for (int j = 0; j < 4; ++j) acc[i][j] = 0.f;

#pragma unroll 4
    for (int k = 0; k < 100; ++k) {
      float a_[4];
#pragma unroll
      for (int i = 0; i < 4; ++i) a_[i] = As[(ty * 4 + i) * 104 + k];
      const float4 bv = *(const float4*)&Bs[k * 128 + tx * 4];
#pragma unroll
      for (int i = 0; i < 4; ++i) {
        acc[i][0] = fmaf(a_[i], bv.x, acc[i][0]);
        acc[i][1] = fmaf(a_[i], bv.y, acc[i][1]);
        acc[i][2] = fmaf(a_[i], bv.z, acc[i][2]);
        acc[i][3] = fmaf(a_[i], bv.w, acc[i][3]);
      }
    }

    const int col4 = nt * 128 + tx * 4;
    if (col4 <= 348) {
#pragma unroll
      for (int i = 0; i < 4; ++i) {
        const int rch = mt * 128 + ty * 4 + i;
        *(float4*)&xwWrite[(size_t)rch * PITCH + col4] =
            make_float4(acc[i][0], acc[i][1], acc[i][2], acc[i][3]);
      }
    }
  }
}

// ---------------------------------------------------------------------------
extern "C" void kernel_launch(void* const* d_in, const int* in_sizes, int n_in,
                              void* d_out, int out_size, void* d_ws, size_t ws_size,
                              hipStream_t stream) {
  const float* x   = (const float*)d_in[0];
  const float* W   = (const float*)d_in[1];
  const float* Wc  = (const float*)d_in[2];
  const float* bv  = (const float*)d_in[3];
  const float* u   = (const float*)d_in[4];
  const float* Wfc = (const float*)d_in[5];
  const float* bfc = (const float*)d_in[6];
  const float* Wz  = (const float*)d_in[7];
  const float* Wr  = (const float*)d_in[8];
  const float* Wh  = (const float*)d_in[9];
  const float* Uz  = (const float*)d_in[10];
  const float* Ur  = (const float*)d_in[11];
  const float* Uh  = (const float*)d_in[12];
  const float* bz  = (const float*)d_in[13];
  const float* br  = (const float*)d_in[14];
  const float* bh  = (const float*)d_in[15];
  float* out = (float*)d_out;
  float* ws  = (float*)d_ws;

  // double-buffered xw; adapt SC to ws capacity
  int SC = 8;
  while (SC > 1 && ((size_t)WS_XW + 2ull * SC * CHUNK_F) * 4 > ws_size) SC >>= 1;
  const int NC = Ss / SC;
  const int nGemm = SC * 50 * 3;  // (SC*128*50/128) mt-tiles x 3 nt-tiles

  float* WT   = ws + WS_WT;
  float* upad = ws + WS_UPAD;
  float* WcT  = ws + WS_WCT;
  float* bpad = ws + WS_BPAD;
  float* hst  = ws + WS_HST;
  float* xw0  = ws + WS_XW;
  float* xw1  = xw0 + (size_t)SC * CHUNK_F;

  k_prep<<<140, 256, 0, stream>>>(W, u, Wc, bv, ws);

  // prologue: gemm chunk 0 -> xw0 (all blocks gemm role)
  k_fused<<<nGemm, 1024, 0, stream>>>(
      x, WT, nullptr, xw0, WcT, bpad, upad, Wfc, bfc,
      Wz, Wr, Wh, Uz, Ur, Uh, bz, br, bh, out, hst,
      0, SC, /*doScan=*/0, /*gemmChunk=*/0, nGemm);

  for (int c = 0; c < NC; ++c) {
    const int withGemm = (c + 1 < NC);
    float* xrd = (c & 1) ? xw1 : xw0;
    float* xwr = (c & 1) ? xw0 : xw1;
    const int grid = SCAN_BLOCKS + (withGemm ? nGemm : 0);
    k_fused<<<grid, 1024, 0, stream>>>(
        x, WT, xrd, xwr, WcT, bpad, upad, Wfc, bfc,
        Wz, Wr, Wh, Uz, Ur, Uh, bz, br, bh, out, hst,
        c, SC, /*doScan=*/1, /*gemmChunk=*/c + 1, withGemm ? nGemm : 0);
  }
}

// Round 6
// 2838.254 us; speedup vs baseline: 1.2944x; 1.2659x over previous
//
#include <hip/hip_runtime.h>
#include <hip/hip_bf16.h>
#include <math.h>

// Problem constants
#define Bb   128
#define Ss   64
#define Tt   50
#define Ff   100
#define DAa  350
#define Rr   30
#define HFCc 100
#define Hh   100
#define PITCH 352   // row pitch (floats) for xw chunk and WT
#define UP    356   // padded d-length (4*89 quads), zero-padded 350..355

// ws layout (float indices), 16B-aligned:
#define WS_WT    0        // 100 x 352 = 35200
#define WS_UPAD  35200    // 30 x 356  = 10680
#define WS_WCT   45880    // 100 x 356 = 35600
#define WS_BPAD  81480    // 356 (pad to 81840)
#define WS_HST   81840    // 128 x 100 = 12800
#define WS_XW    94640    // two chunk buffers, each SC*2252800 floats

#define SCAN_BLOCKS 128
#define CHUNK_F 2252800   // floats per SC=1 chunk unit (128*50*352)

// scan-role LDS arena offsets (floats)
#define L_SCR  0        // 12800 part_s / phase partials
#define L_AIT  12800    // 1500
#define L_MS   14300    // 30*104 = 3120
#define L_XL   17420    // 5000 x-tile
#define L_CTX  22420    // 356
#define L_H    22776
#define L_FC   22876
#define L_Z    22976
#define L_RG   23076
#define L_HC1  23176
#define ARENA  26112    // max(scan 23276, gemm 13312+12800)

__device__ __forceinline__ float ftanh(float x) {
  const float t = __expf(2.0f * x);
  return 1.0f - __fdividef(2.0f, t + 1.0f);   // inf-safe at both ends
}
__device__ __forceinline__ float fsig(float x) {
  return __fdividef(1.0f, 1.0f + __expf(-x));
}

// ---------------------------------------------------------------------------
__global__ __launch_bounds__(256) void k_prep(const float* __restrict__ W,
                                              const float* __restrict__ u,
                                              const float* __restrict__ Wc,
                                              const float* __restrict__ bvec,
                                              float* __restrict__ ws) {
  int i = blockIdx.x * 256 + threadIdx.x;
  if (i < 100 * PITCH) {
    int k = i / PITCH, col = i % PITCH;
    ws[WS_WT + i] = (col < DAa) ? W[col * Ff + k] : 0.0f;
  }
  if (i < Rr * UP) {
    int r = i / UP, d = i % UP;
    ws[WS_UPAD + i] = (d < DAa) ? u[r * DAa + d] : 0.0f;
  }
  if (i < Hh * UP) {
    int k = i / UP, d = i % UP;
    ws[WS_WCT + i] = (d < DAa) ? Wc[d * Hh + k] : 0.0f;
  }
  if (i < UP) ws[WS_BPAD + i] = (i < DAa) ? bvec[i] : 0.0f;
}

// ---------------------------------------------------------------------------
// Fused kernel. Blocks [0,128) (when doScan): persistent per-b scan of chunk c.
// Remaining blocks: GEMM tiles of chunk gemmChunk -> xwWrite. 1024 threads.
// ---------------------------------------------------------------------------
__global__ __launch_bounds__(1024) void k_fused(
    const float* __restrict__ x, const float* __restrict__ WT,
    const float* __restrict__ xwRead, float* __restrict__ xwWrite,
    const float* __restrict__ WcT, const float* __restrict__ b_pad,
    const float* __restrict__ u_pad, const float* __restrict__ Wfc,
    const float* __restrict__ bfc,
    const float* __restrict__ Wz, const float* __restrict__ Wr,
    const float* __restrict__ Wh, const float* __restrict__ Uz,
    const float* __restrict__ Ur, const float* __restrict__ Uh,
    const float* __restrict__ bz, const float* __restrict__ br,
    const float* __restrict__ bh,
    float* __restrict__ out, float* __restrict__ hstate,
    int c, int SC, int doScan, int gemmChunk, int nGemm) {
  __shared__ __align__(16) float smem[ARENA];  // 104.4 KB

  const int tid = threadIdx.x;
  const int bid = blockIdx.x;

  if (doScan && bid < SCAN_BLOCKS) {
    // ---------------- scan role ----------------
    float* scratch = smem + L_SCR;
    float* ait     = smem + L_AIT;
    float* M_s     = smem + L_MS;
    float* x_lds   = smem + L_XL;
    float* ctx     = smem + L_CTX;
    float* h_sm    = smem + L_H;
    float* fc_sm   = smem + L_FC;
    float* z_sm    = smem + L_Z;
    float* rg_sm   = smem + L_RG;
    float* hc1_sm  = smem + L_HC1;

    const int b = bid;
    const int lane = tid & 63;
    const int w = tid >> 6;                      // 0..15
    const int wu = __builtin_amdgcn_readfirstlane(w);
    const int seg = wu & 7;                      // d-segment (11 quads each)
    const int half = wu >> 3;                    // r-half
    const int q0 = seg * 11;                     // quads 0..87 covered
    const int tl = (lane < Tt) ? lane : (Tt - 1);

    if (tid < Hh) h_sm[tid] = (c == 0) ? 0.f : hstate[b * Hh + tid];
    __syncthreads();

    for (int sl = 0; sl < SC; ++sl) {
      const int sg = c * SC + sl;

      // ---- pre-P1: issue x-tile loads (reg staging; written in P2)
      const float* xsrc = &x[(size_t)(b * Ss + sg) * Tt * Ff];
      float4 xs0, xs1;
      if (tid < 1250) xs0 = *(const float4*)&xsrc[tid * 4];
      if (tid < 226)  xs1 = *(const float4*)&xsrc[(tid + 1024) * 4];

      // ---- P1: ctx partials: 712 thr = ks(8) x dq(89)
      if (tid < 712) {
        const int ks = tid / 89, dq = tid % 89;
        const int k0 = (ks < 4) ? 13 * ks : 52 + 12 * (ks - 4);
        const int kl = (ks < 4) ? 13 : 12;
        float4 a = make_float4(0.f, 0.f, 0.f, 0.f);
        const float* wp = &WcT[k0 * UP + dq * 4];
        for (int k = 0; k < kl; ++k) {
          const float hk = h_sm[k0 + k];
          const float4 wv = *(const float4*)&wp[k * UP];
          a.x = fmaf(wv.x, hk, a.x); a.y = fmaf(wv.y, hk, a.y);
          a.z = fmaf(wv.z, hk, a.z); a.w = fmaf(wv.w, hk, a.w);
        }
        *(float4*)&scratch[ks * UP + dq * 4] = a;
      }
      __syncthreads();

      // ---- P2: ctx combine + x-tile LDS write
      if (tid < 356) {
        float v = b_pad[tid];
#pragma unroll
        for (int ks = 0; ks < 8; ++ks) v += scratch[ks * UP + tid];
        ctx[tid] = v;
      }
      if (tid < 1250) *(float4*)&x_lds[tid * 4] = xs0;
      if (tid < 226)  *(float4*)&x_lds[(tid + 1024) * 4] = xs1;
      __syncthreads();

      // ---- P3: fused tanh+ait partials: 16 waves = 8 d-segs x 2 r-halves
      {
        float pacc[15];
#pragma unroll
        for (int ri = 0; ri < 15; ++ri) pacc[ri] = 0.f;
        const float* xwrow = &xwRead[((size_t)(b * SC + sl) * Tt + tl) * PITCH];
#pragma unroll 2
        for (int q = q0; q < q0 + 11; ++q) {
          const float4 xv = *(const float4*)&xwrow[q * 4];
          const float4 cv = *(const float4*)&ctx[q * 4];
          const float a0 = ftanh(xv.x + cv.x);
          const float a1 = ftanh(xv.y + cv.y);
          const float a2 = ftanh(xv.z + cv.z);
          const float a3 = ftanh(xv.w + cv.w);
#pragma unroll
          for (int ri = 0; ri < 15; ++ri) {
            const float4 uv = *(const float4*)&u_pad[(half * 15 + ri) * UP + q * 4];
            pacc[ri] = fmaf(a0, uv.x,
                        fmaf(a1, uv.y,
                         fmaf(a2, uv.z,
                          fmaf(a3, uv.w, pacc[ri]))));
          }
        }
        if (lane < Tt) {
#pragma unroll
          for (int ri = 0; ri < 15; ++ri)
            scratch[w * 800 + ri * Tt + lane] = pacc[ri];
        }
      }
      __syncthreads();

      // ---- P4: merged reduce + softmax over reshaped rows (480 thr)
      if (tid < 480) {
        const int rr = tid >> 4, l = tid & 15;
        float e[4];
        float m = -1e30f;
        int cnt = 0;
        for (int i = l; i < Tt; i += 16) {
          const int idx = rr * Tt + i;        // flat reshaped index
          const int t = idx / Rr, r = idx - t * Rr;
          const int hf = (r >= 15) ? 1 : 0, ri = r - hf * 15;
          float s = 0.f;
#pragma unroll
          for (int sg2 = 0; sg2 < 8; ++sg2)
            s += scratch[(hf * 8 + sg2) * 800 + ri * Tt + t];
          e[cnt++] = s;
          m = fmaxf(m, s);
        }
#pragma unroll
        for (int o = 8; o >= 1; o >>= 1) m = fmaxf(m, __shfl_xor(m, o, 16));
        float ssum = 0.f;
#pragma unroll 4
        for (int k = 0; k < cnt; ++k) { e[k] = __expf(e[k] - m); ssum += e[k]; }
#pragma unroll
        for (int o = 8; o >= 1; o >>= 1) ssum += __shfl_xor(ssum, o, 16);
        const float inv = __fdividef(1.0f, ssum);
        cnt = 0;
        for (int i = l; i < Tt; i += 16) ait[rr * Tt + i] = e[cnt++] * inv;
      }
      __syncthreads();

      // ---- P5: M[r][f4] = sum_t A[r][t] * x_lds[t][f4]  (750 thr, f4)
      if (tid < 750) {
        const int r = tid / 25, f4i = tid % 25;
        float4 acc = make_float4(0.f, 0.f, 0.f, 0.f);
#pragma unroll
        for (int t = 0; t < Tt; ++t) {
          const float a = ait[r * Tt + t];
          const float4 xv = *(const float4*)&x_lds[t * 100 + f4i * 4];
          acc.x = fmaf(a, xv.x, acc.x); acc.y = fmaf(a, xv.y, acc.y);
          acc.z = fmaf(a, xv.z, acc.z); acc.w = fmaf(a, xv.w, acc.w);
        }
        *(float4*)&M_s[r * 104 + f4i * 4] = acc;
      }
      __syncthreads();

      // ---- P6: fc partials (750) + GRU h-side partials Uz/Ur (200)
      if (tid < 750) {
        const int r = tid / 25, jq = tid % 25;
        float4 a = make_float4(0.f, 0.f, 0.f, 0.f);
        const float* wp = &Wfc[(size_t)(r * 100) * 100 + jq * 4];
#pragma unroll 8
        for (int f2 = 0; f2 < 100; ++f2) {
          const float mv = M_s[r * 104 + f2];
          const float4 wv = *(const float4*)&wp[(size_t)f2 * 100];
          a.x = fmaf(mv, wv.x, a.x); a.y = fmaf(mv, wv.y, a.y);
          a.z = fmaf(mv, wv.z, a.z); a.w = fmaf(mv, wv.w, a.w);
        }
        *(float4*)&scratch[r * 100 + jq * 4] = a;
      } else if (tid < 950) {
        const int tt = tid - 750, pr = tt / 100, rem = tt % 100;
        const int ks = rem / 25, jq = rem % 25;
        const float* Um = pr ? Ur : Uz;
        float4 a = make_float4(0.f, 0.f, 0.f, 0.f);
        const float* up = &Um[ks * 25 * 100 + jq * 4];
#pragma unroll 5
        for (int k = 0; k < 25; ++k) {
          const float hv = h_sm[ks * 25 + k];
          const float4 uv = *(const float4*)&up[k * 100];
          a.x = fmaf(hv, uv.x, a.x); a.y = fmaf(hv, uv.y, a.y);
          a.z = fmaf(hv, uv.z, a.z); a.w = fmaf(hv, uv.w, a.w);
        }
        *(float4*)&scratch[3000 + (pr * 4 + ks) * 100 + jq * 4] = a;
      }
      __syncthreads();

      // ---- P7: fc combine
      if (tid < 100) {
        float v = bfc[tid];
#pragma unroll
        for (int r = 0; r < 30; ++r) v += scratch[r * 100 + tid];
        fc_sm[tid] = fmaxf(v, 0.f);
      }
      __syncthreads();

      // ---- P8: GRU gates: full fc-side dot + Uz/Ur partial combine (300 thr)
      if (tid < 300) {
        const int unit = tid / 100, j = tid % 100;
        const float* Wm = (unit == 0) ? Wz : (unit == 1) ? Wr : Wh;
        float acc = (unit == 0) ? bz[j] : (unit == 1) ? br[j] : bh[j];
        if (unit < 2) {
#pragma unroll
          for (int i = 0; i < 4; ++i)
            acc += scratch[3000 + (unit * 4 + i) * 100 + j];
        }
#pragma unroll 10
        for (int k = 0; k < 100; ++k) acc = fmaf(fc_sm[k], Wm[k * 100 + j], acc);
        if (unit == 0)      z_sm[j] = fsig(acc);
        else if (unit == 1) rg_sm[j] = fsig(acc);
        else                hc1_sm[j] = acc;
      }
      __syncthreads();

      // ---- P9: hp partials: 500 thr = ks(20, 5 k's) x jq(25)
      if (tid < 500) {
        const int ks = tid / 25, jq = tid % 25, k0 = ks * 5;
        float4 a = make_float4(0.f, 0.f, 0.f, 0.f);
        const float* up = &Uh[k0 * 100 + jq * 4];
#pragma unroll
        for (int k = 0; k < 5; ++k) {
          const float rv = rg_sm[k0 + k] * h_sm[k0 + k];
          const float4 uv = *(const float4*)&up[k * 100];
          a.x = fmaf(rv, uv.x, a.x); a.y = fmaf(rv, uv.y, a.y);
          a.z = fmaf(rv, uv.z, a.z); a.w = fmaf(rv, uv.w, a.w);
        }
        *(float4*)&scratch[ks * 100 + jq * 4] = a;
      }
      __syncthreads();

      // ---- P10: final h update
      if (tid < 100) {
        const int j = tid;
        float a = hc1_sm[j];
#pragma unroll
        for (int ks = 0; ks < 20; ++ks) a += scratch[ks * 100 + j];
        const float hp = ftanh(a);
        const float z = z_sm[j];
        const float hn = (1.0f - z) * h_sm[j] + z * hp;
        out[((size_t)b * Ss + sg) * Hh + j] = hn;
        h_sm[j] = hn;
      }
      __syncthreads();
    }

    if (tid < Hh) hstate[b * Hh + tid] = h_sm[tid];

  } else {
    // ---------------- gemm role: BM=128, BN=128, K=100 ----------------
    const int g = doScan ? (bid - SCAN_BLOCKS) : bid;
    if (g >= nGemm) return;
    float* As = smem;            // 128 x 104 = 13312
    float* Bs = smem + 13312;    // 100 x 128 = 12800

    const int mt = g / 3, nt = g % 3;
    const int rowsPerB = SC * Tt;

    for (int i = tid; i < 3200; i += 1024) {   // A: 128 rows x 25 f4
      const int m = i / 25, k4 = (i % 25) * 4;
      const int rch = mt * 128 + m;
      const int b = rch / rowsPerB, rem = rch % rowsPerB;
      const int sl = rem / Tt, t = rem % Tt;
      *(float4*)&As[m * 104 + k4] =
          *(const float4*)&x[((size_t)((b * Ss + gemmChunk * SC + sl) * Tt) + t) * Ff + k4];
    }
    for (int i = tid; i < 3200; i += 1024) {   // B: 100 k x 32 f4
      const int k = i / 32, j4 = (i % 32) * 4;
      const int col = nt * 128 + j4;
      float4 v = make_float4(0.f, 0.f, 0.f, 0.f);
      if (col < PITCH) v = *(const float4*)&WT[k * PITCH + col];
      *(float4*)&Bs[k * 128 + j4] = v;
    }
    __syncthreads();

    const int tx = tid & 31, ty = tid >> 5;    // 32x32 threads, 4x4 each
    float acc[4][4];
#pragma unroll
    for (int i = 0; i < 4; ++i)
#pragma unroll
      for (int j = 0; j < 4; ++j) acc[i][j] = 0.f;

#pragma unroll 4
    for (int k = 0; k < 100; ++k) {
      float a_[4];
#pragma unroll
      for (int i = 0; i < 4; ++i) a_[i] = As[(ty * 4 + i) * 104 + k];
      const float4 bv = *(const float4*)&Bs[k * 128 + tx * 4];
#pragma unroll
      for (int i = 0; i < 4; ++i) {
        acc[i][0] = fmaf(a_[i], bv.x, acc[i][0]);
        acc[i][1] = fmaf(a_[i], bv.y, acc[i][1]);
        acc[i][2] = fmaf(a_[i], bv.z, acc[i][2]);
        acc[i][3] = fmaf(a_[i], bv.w, acc[i][3]);
      }
    }

    const int col4 = nt * 128 + tx * 4;
    if (col4 <= 348) {
#pragma unroll
      for (int i = 0; i < 4; ++i) {
        const int rch = mt * 128 + ty * 4 + i;
        *(float4*)&xwWrite[(size_t)rch * PITCH + col4] =
            make_float4(acc[i][0], acc[i][1], acc[i][2], acc[i][3]);
      }
    }
  }
}

// ---------------------------------------------------------------------------
extern "C" void kernel_launch(void* const* d_in, const int* in_sizes, int n_in,
                              void* d_out, int out_size, void* d_ws, size_t ws_size,
                              hipStream_t stream) {
  const float* x   = (const float*)d_in[0];
  const float* W   = (const float*)d_in[1];
  const float* Wc  = (const float*)d_in[2];
  const float* bv  = (const float*)d_in[3];
  const float* u   = (const float*)d_in[4];
  const float* Wfc = (const float*)d_in[5];
  const float* bfc = (const float*)d_in[6];
  const float* Wz  = (const float*)d_in[7];
  const float* Wr  = (const float*)d_in[8];
  const float* Wh  = (const float*)d_in[9];
  const float* Uz  = (const float*)d_in[10];
  const float* Ur  = (const float*)d_in[11];
  const float* Uh  = (const float*)d_in[12];
  const float* bz  = (const float*)d_in[13];
  const float* br  = (const float*)d_in[14];
  const float* bh  = (const float*)d_in[15];
  float* out = (float*)d_out;
  float* ws  = (float*)d_ws;

  // double-buffered xw; adapt SC to ws capacity
  int SC = 8;
  while (SC > 1 && ((size_t)WS_XW + 2ull * SC * CHUNK_F) * 4 > ws_size) SC >>= 1;
  const int NC = Ss / SC;
  const int nGemm = SC * 50 * 3;  // (SC*128*50/128) mt-tiles x 3 nt-tiles

  float* WT   = ws + WS_WT;
  float* upad = ws + WS_UPAD;
  float* WcT  = ws + WS_WCT;
  float* bpad = ws + WS_BPAD;
  float* hst  = ws + WS_HST;
  float* xw0  = ws + WS_XW;
  float* xw1  = xw0 + (size_t)SC * CHUNK_F;

  k_prep<<<140, 256, 0, stream>>>(W, u, Wc, bv, ws);

  // prologue: gemm chunk 0 -> xw0 (all blocks gemm role)
  k_fused<<<nGemm, 1024, 0, stream>>>(
      x, WT, nullptr, xw0, WcT, bpad, upad, Wfc, bfc,
      Wz, Wr, Wh, Uz, Ur, Uh, bz, br, bh, out, hst,
      0, SC, /*doScan=*/0, /*gemmChunk=*/0, nGemm);

  for (int c = 0; c < NC; ++c) {
    const int withGemm = (c + 1 < NC);
    float* xrd = (c & 1) ? xw1 : xw0;
    float* xwr = (c & 1) ? xw0 : xw1;
    const int grid = SCAN_BLOCKS + (withGemm ? nGemm : 0);
    k_fused<<<grid, 1024, 0, stream>>>(
        x, WT, xrd, xwr, WcT, bpad, upad, Wfc, bfc,
        Wz, Wr, Wh, Uz, Ur, Uh, bz, br, bh, out, hst,
        c, SC, /*doScan=*/1, /*gemmChunk=*/c + 1, withGemm ? nGemm : 0);
  }
}